// Round 1
// baseline (1434.376 us; speedup 1.0000x reference)
//
#include <hip/hip_runtime.h>
#include <stdint.h>

typedef __bf16 bf16x8 __attribute__((ext_vector_type(8)));
typedef float  floatx4 __attribute__((ext_vector_type(4)));

#define T_LEN 512
#define I_DIM 64
#define H_DIM 128
#define BT    16      // batch rows per block
#define NTHR  512     // 8 waves

// LDS row strides (padded: stride mod 32 dwords == 4 -> 2-way bank aliasing, free)
#define PS  516       // preact row stride (fp32); cols 0-127 r, 128-255 z, 256-383 i_n, 384-511 h_n
#define XS  72        // x_t row stride (bf16)
#define HFS 132       // h fp32 row stride
#define HBS 136       // h bf16 row stride (272B, 16B-aligned rows)

__device__ __forceinline__ uint16_t f2bfbits(float f) {
    union { float f; uint32_t u; } v; v.f = f;
    uint32_t r = v.u + 0x7FFFu + ((v.u >> 16) & 1u);   // RNE
    return (uint16_t)(r >> 16);
}
__device__ __forceinline__ __bf16 bits2bf(uint16_t u) {
    union { uint16_t u; __bf16 b; } x; x.u = u; return x.b;
}
__device__ __forceinline__ float sigm(float x) {
    return __builtin_amdgcn_rcpf(1.f + exp2f(-1.4426950408889634f * x));
}
__device__ __forceinline__ float tanh_fast(float x) {
    return 2.f * __builtin_amdgcn_rcpf(1.f + exp2f(-2.8853900817779268f * x)) - 1.f;
}

#define MFMA(a,b,c) __builtin_amdgcn_mfma_f32_16x16x32_bf16((a),(b),(c),0,0,0)

__global__ __launch_bounds__(NTHR, 2) void gru_fused(
    const float* __restrict__ x,
    const float* __restrict__ Wih0, const float* __restrict__ Whh0,
    const float* __restrict__ bih0, const float* __restrict__ bhh0,
    const float* __restrict__ Wih1, const float* __restrict__ Whh1,
    const float* __restrict__ bih1, const float* __restrict__ bhh1,
    const float* __restrict__ Wfc,  const float* __restrict__ bfc,
    float* __restrict__ out)
{
    __shared__ __align__(16) float  P[BT * PS];       // 33024 B
    __shared__ __align__(16) __bf16 xb[BT * XS];      //  2304 B
    __shared__ __align__(16) float  h0f[BT * HFS];    //  8448 B
    __shared__ __align__(16) __bf16 h0b[BT * HBS];    //  4352 B
    __shared__ __align__(16) float  h1f[BT * HFS];    //  8448 B
    __shared__ __align__(16) __bf16 h1b[BT * HBS];    //  4352 B
    __shared__ __align__(16) float  bias0[512];       //  2048 B
    __shared__ __align__(16) float  bias1[512];       //  2048 B  -> total 65024 B

    const int tid  = threadIdx.x;
    const int lane = tid & 63;
    const int wave = tid >> 6;           // 0..7
    const int ln16 = lane & 15;
    const int q8   = (lane >> 4) * 8;    // k sub-offset within a 32-chunk
    const int brow = blockIdx.x * BT;

    // ---- biases: layout matches preact columns ----
    {
        int c = tid; float v0, v1;
        if (c < 256)      { v0 = bih0[c] + bhh0[c]; v1 = bih1[c] + bhh1[c]; }
        else if (c < 384) { v0 = bih0[c];           v1 = bih1[c]; }
        else              { v0 = bhh0[c - 128];     v1 = bhh1[c - 128]; }
        bias0[c] = v0; bias1[c] = v1;
    }
    for (int i = tid; i < BT * HFS; i += NTHR) { h0f[i] = 0.f; h1f[i] = 0.f; }
    for (int i = tid; i < BT * HBS; i += NTHR) { h0b[i] = (__bf16)0.f; h1b[i] = (__bf16)0.f; }

    // ---- weights resident in registers as MFMA B-fragments ----
    // wave owns col-tiles: r @ rows [16w,16w+16), z @ 128+, n @ 256+
    bf16x8 wgi0[3][2], wgh0[3][4], wgi1[3][4], wgh1[3][4];
    {
        const int tb0 = wave * 16, tb1 = 128 + wave * 16, tb2 = 256 + wave * 16;
        const int tbs[3] = { tb0, tb1, tb2 };
        #pragma unroll
        for (int g = 0; g < 3; ++g) {
            const float* p0 = Wih0 + (size_t)(tbs[g] + ln16) * 64  + q8;
            const float* p1 = Whh0 + (size_t)(tbs[g] + ln16) * 128 + q8;
            const float* p2 = Wih1 + (size_t)(tbs[g] + ln16) * 128 + q8;
            const float* p3 = Whh1 + (size_t)(tbs[g] + ln16) * 128 + q8;
            #pragma unroll
            for (int q = 0; q < 2; ++q) {
                bf16x8 r;
                #pragma unroll
                for (int j = 0; j < 8; ++j) r[j] = bits2bf(f2bfbits(p0[q * 32 + j]));
                wgi0[g][q] = r;
            }
            #pragma unroll
            for (int q = 0; q < 4; ++q) {
                bf16x8 r1, r2, r3;
                #pragma unroll
                for (int j = 0; j < 8; ++j) {
                    r1[j] = bits2bf(f2bfbits(p1[q * 32 + j]));
                    r2[j] = bits2bf(f2bfbits(p2[q * 32 + j]));
                    r3[j] = bits2bf(f2bfbits(p3[q * 32 + j]));
                }
                wgh0[g][q] = r1; wgi1[g][q] = r2; wgh1[g][q] = r3;
            }
        }
    }
    __syncthreads();

    // ---- x streaming: 2 floats/thread/step, software-prefetched one step ahead ----
    const int xr = (tid * 2) >> 6;           // row 0..15
    const int xi = (tid * 2) & 63;           // i   0..62 even
    const float* xptr = x + (size_t)(brow + xr) * T_LEN * I_DIM + xi;
    float2 vx = *(const float2*)xptr;        // t = 0

    const int grow = tid >> 5;               // gate row 0..15
    const int gj   = tid & 31;

    for (int t = 0; t < T_LEN; ++t) {
        xb[xr * XS + xi]     = bits2bf(f2bfbits(vx.x));
        xb[xr * XS + xi + 1] = bits2bf(f2bfbits(vx.y));
        if (t + 1 < T_LEN) vx = *(const float2*)(xptr + (size_t)(t + 1) * I_DIM);
        __syncthreads();   // B1: xb ready; h0b/h1b hold h_{t-1}

        // ======== layer 0: gi0 (x·Wih0^T) + gh0 (h0·Whh0^T) ========
        {
            floatx4 aR = {0,0,0,0}, aZ = {0,0,0,0}, aNi = {0,0,0,0}, aNh = {0,0,0,0};
            #pragma unroll
            for (int q = 0; q < 2; ++q) {
                bf16x8 a = *(const bf16x8*)&xb[ln16 * XS + q * 32 + q8];
                aR  = MFMA(a, wgi0[0][q], aR);
                aZ  = MFMA(a, wgi0[1][q], aZ);
                aNi = MFMA(a, wgi0[2][q], aNi);
            }
            #pragma unroll
            for (int q = 0; q < 4; ++q) {
                bf16x8 a = *(const bf16x8*)&h0b[ln16 * HBS + q * 32 + q8];
                aR  = MFMA(a, wgh0[0][q], aR);
                aZ  = MFMA(a, wgh0[1][q], aZ);
                aNh = MFMA(a, wgh0[2][q], aNh);
            }
            const int col = wave * 16 + ln16;
            #pragma unroll
            for (int i = 0; i < 4; ++i) {     // C/D: col=lane&15, row=(lane>>4)*4+i
                const int row = (lane >> 4) * 4 + i;
                P[row * PS + col]       = aR[i];
                P[row * PS + 128 + col] = aZ[i];
                P[row * PS + 256 + col] = aNi[i];
                P[row * PS + 384 + col] = aNh[i];
            }
        }
        __syncthreads();   // B2: layer0 preacts ready

        #pragma unroll
        for (int m = 0; m < 4; ++m) {
            const int j = gj + 32 * m;
            const float pr  = P[grow * PS + j]       + bias0[j];
            const float pz  = P[grow * PS + 128 + j] + bias0[128 + j];
            const float pin = P[grow * PS + 256 + j] + bias0[256 + j];
            const float phn = P[grow * PS + 384 + j] + bias0[384 + j];
            const float r = sigm(pr);
            const float z = sigm(pz);
            const float n = tanh_fast(pin + r * phn);
            const float hp = h0f[grow * HFS + j];
            const float hn = (1.f - z) * n + z * hp;
            h0f[grow * HFS + j] = hn;
            h0b[grow * HBS + j] = bits2bf(f2bfbits(hn));
        }
        __syncthreads();   // B3: h0 (= layer1 input) ready

        // ======== layer 1: gi1 (h0·Wih1^T) + gh1 (h1·Whh1^T) ========
        {
            floatx4 aR = {0,0,0,0}, aZ = {0,0,0,0}, aNi = {0,0,0,0}, aNh = {0,0,0,0};
            #pragma unroll
            for (int q = 0; q < 4; ++q) {
                bf16x8 a = *(const bf16x8*)&h0b[ln16 * HBS + q * 32 + q8];
                aR  = MFMA(a, wgi1[0][q], aR);
                aZ  = MFMA(a, wgi1[1][q], aZ);
                aNi = MFMA(a, wgi1[2][q], aNi);
            }
            #pragma unroll
            for (int q = 0; q < 4; ++q) {
                bf16x8 a = *(const bf16x8*)&h1b[ln16 * HBS + q * 32 + q8];
                aR  = MFMA(a, wgh1[0][q], aR);
                aZ  = MFMA(a, wgh1[1][q], aZ);
                aNh = MFMA(a, wgh1[2][q], aNh);
            }
            const int col = wave * 16 + ln16;
            #pragma unroll
            for (int i = 0; i < 4; ++i) {
                const int row = (lane >> 4) * 4 + i;
                P[row * PS + col]       = aR[i];
                P[row * PS + 128 + col] = aZ[i];
                P[row * PS + 256 + col] = aNi[i];
                P[row * PS + 384 + col] = aNh[i];
            }
        }
        __syncthreads();   // B4: layer1 preacts ready

        #pragma unroll
        for (int m = 0; m < 4; ++m) {
            const int j = gj + 32 * m;
            const float pr  = P[grow * PS + j]       + bias1[j];
            const float pz  = P[grow * PS + 128 + j] + bias1[128 + j];
            const float pin = P[grow * PS + 256 + j] + bias1[256 + j];
            const float phn = P[grow * PS + 384 + j] + bias1[384 + j];
            const float r = sigm(pr);
            const float z = sigm(pz);
            const float n = tanh_fast(pin + r * phn);
            const float hp = h1f[grow * HFS + j];
            const float hn = (1.f - z) * n + z * hp;
            h1f[grow * HFS + j] = hn;
            h1b[grow * HBS + j] = bits2bf(f2bfbits(hn));
        }
        // no trailing barrier: loop-top only writes xb (not read after B2), B1 re-syncs
    }
    __syncthreads();

    // ---- final FC: out[b] = h1_final[b,:] . Wfc + bfc ----
    {
        const int l = tid & 31;   // 32 lanes per row, grow = row
        float s = 0.f;
        #pragma unroll
        for (int m = 0; m < 4; ++m) {
            const int j = l + 32 * m;
            s += h1f[grow * HFS + j] * Wfc[j];
        }
        #pragma unroll
        for (int d = 16; d >= 1; d >>= 1) s += __shfl_down(s, d, 32);
        if (l == 0) out[brow + grow] = s + bfc[0];
    }
}

extern "C" void kernel_launch(void* const* d_in, const int* in_sizes, int n_in,
                              void* d_out, int out_size, void* d_ws, size_t ws_size,
                              hipStream_t stream) {
    const float* x    = (const float*)d_in[0];
    const float* Wih0 = (const float*)d_in[1];
    const float* Whh0 = (const float*)d_in[2];
    const float* bih0 = (const float*)d_in[3];
    const float* bhh0 = (const float*)d_in[4];
    const float* Wih1 = (const float*)d_in[5];
    const float* Whh1 = (const float*)d_in[6];
    const float* bih1 = (const float*)d_in[7];
    const float* bhh1 = (const float*)d_in[8];
    const float* Wfc  = (const float*)d_in[9];
    const float* bfc  = (const float*)d_in[10];
    float* out = (float*)d_out;

    hipLaunchKernelGGL(gru_fused, dim3(512 / BT), dim3(NTHR), 0, stream,
                       x, Wih0, Whh0, bih0, bhh0, Wih1, Whh1, bih1, bhh1, Wfc, bfc, out);
}